// Round 5
// baseline (128.761 us; speedup 1.0000x reference)
//
#include <hip/hip_runtime.h>
#include <cstdint>

// Problem constants
constexpr int kN   = 4;
constexpr int kC   = 256;
constexpr int kS   = 2304;   // 48*48
constexpr int kDK  = 256;
constexpr int kDV  = 256;
constexpr int kDH  = 32;     // head dim
constexpr int kO   = 768;    // 2*DK + DV

typedef __bf16    bf16x8 __attribute__((ext_vector_type(8)));
typedef float     f32x4  __attribute__((ext_vector_type(4)));
typedef float     f32x16 __attribute__((ext_vector_type(16)));
typedef _Float16  f16;
typedef _Float16  f16x2  __attribute__((ext_vector_type(2)));
typedef _Float16  f16x4  __attribute__((ext_vector_type(4)));
typedef _Float16  f16x8  __attribute__((ext_vector_type(8)));

union U4  { uint4 u; bf16x8 v; unsigned short s[8]; };
union F4  { float4 f; float a[4]; };
union UF8 { uint4 u; f16x8 v; f16 h[8]; };
union UF4 { uint2 u; f16x4 v; ushort4 su; };

#if __has_builtin(__builtin_amdgcn_exp2f)
#define EXP2(x) __builtin_amdgcn_exp2f(x)
#else
#define EXP2(x) exp2f(x)
#endif

__device__ inline unsigned int pk2(float a, float b) {
    auto p = __builtin_amdgcn_cvt_pkrtz(a, b);
    return __builtin_bit_cast(unsigned int, p);
}
// f16 hi/lo split: h captures 11 mantissa bits, l the next 11 (~22-bit exact).
__device__ inline void split2f(float v, f16& h, f16& l) {
    h = (f16)v;
    l = (f16)(v - (float)h);
}

// Fragment layouts:
// 16x16x32 (correctness-verified rounds 6-10; dtype-independent):
//   A/B-frag elem (row, k): lane = ((k>>3)&3)*16 + (row&15), j = k&7
//   C-layout: D[row = (lane>>4)*4 + reg][col = lane&15].
// 32x32x16 (attn core, r1-verified):
//   A-frag (row, k): lane = (k>>3)*32 + (row&31), j = k&7  (B symmetric, col=lane&31)
//   C-layout: D[row = (reg&3) + 8*(reg>>2) + 4*(lane>>5)][col = lane&31].

// ---------------------------------------------------------------------------
// prep_w (r3-verified): w_qkv -> SPLIT-F16 B-frags wh/wl [otile 48][kt 8]
// [lane][8]; w_proj -> f16 A-frag wp. Grid 128.
// ---------------------------------------------------------------------------
__global__ __launch_bounds__(256) void prep_w(const float* __restrict__ w_qkv,
                                              const float* __restrict__ w_proj,
                                              unsigned short* __restrict__ wh,
                                              unsigned short* __restrict__ wl,
                                              f16* __restrict__ wp) {
    int idx = blockIdx.x * 256 + threadIdx.x;
    if (idx < 24576) {           // w_qkv: 768 o x 32 c-groups
        int o = idx >> 5, cg = idx & 31;
        F4 a0, a1;
        a0.f = *(const float4*)(w_qkv + (size_t)o * kC + cg * 8);
        a1.f = *(const float4*)(w_qkv + (size_t)o * kC + cg * 8 + 4);
        UF8 hv, lv;
#pragma unroll
        for (int j = 0; j < 4; j++) split2f(a0.a[j], hv.h[j], lv.h[j]);
#pragma unroll
        for (int j = 0; j < 4; j++) split2f(a1.a[j], hv.h[j + 4], lv.h[j + 4]);
        size_t frag = ((size_t)(o >> 4) * 8 + (cg >> 2)) * 512 + ((cg & 3) * 16 + (o & 15)) * 8;
        *(uint4*)(wh + frag) = hv.u;
        *(uint4*)(wl + frag) = lv.u;
    } else {                     // w_proj: 256 o x 32 dv-groups
        int i2 = idx - 24576;
        int o = i2 >> 5, cg = i2 & 31;
        F4 a0, a1;
        a0.f = *(const float4*)(w_proj + (size_t)o * kDV + cg * 8);
        a1.f = *(const float4*)(w_proj + (size_t)o * kDV + cg * 8 + 4);
        UF8 w;
#pragma unroll
        for (int j = 0; j < 4; j++) w.h[j] = (f16)a0.a[j];
#pragma unroll
        for (int j = 0; j < 4; j++) w.h[j + 4] = (f16)a1.a[j];
        size_t frag = ((size_t)(o >> 4) * 8 + (cg >> 2)) * 512 + ((cg & 3) * 16 + (o & 15)) * 8;
        *(uint4*)(wp + frag) = w.u;
    }
}

// ---------------------------------------------------------------------------
// gemm_qkv v5: merge the oh dimension — one block covers 32 s x ALL 768 o,
// so the x strip is staged ONCE (r4 staged it 3x, once per K/Q/V section).
// 512 thr = 8 waves, each 32s x 96o (6 o-tiles; acc 2x6). Staging: 16 f32
// loads/thread -> 16 KB f16 A-frag LDS. 2-MFMA split-f16-w scheme
// (r3-verified numerics). Epilogue dispatches per 16-o tile on section
// (boundaries at 256/512 are o-tile-aligned -> wave-uniform per nt).
// Grid (72, 1, 4) x 512 thr; launch_bounds(512,4) targets <=128 regs
// (2 blocks/CU capacity, no stragglers at 288 blocks).
// ---------------------------------------------------------------------------
__global__ __launch_bounds__(512, 4) void gemm_qkv(const float* __restrict__ x,
                                                   const unsigned short* __restrict__ wh,
                                                   const unsigned short* __restrict__ wl,
                                                   const float* __restrict__ bias,
                                                   f16* __restrict__ Qf,
                                                   f16* __restrict__ Kf,
                                                   f16* __restrict__ Vp) {
    int sb = blockIdx.x, n = blockIdx.z;
    int tid  = threadIdx.x;
    int wid  = tid >> 6;          // o-strip 0..7 (96 o each)
    int lane = tid & 63;
    int l15  = lane & 15;
    int quad = lane >> 4;
    int s0   = sb * 32;

    __shared__ unsigned short AH[8192];   // f16 bits, [kt 8][mt 2][lane 64][8]

    // ---- stage x strip [32 s][256 c] -> f16 A-frag LDS (once per block) ----
    {
        int cg = tid >> 5;          // 0..15
        int sl = tid & 31;          // s within strip
        const float* xb = x + (size_t)n * kC * kS + s0 + sl;
#pragma unroll
        for (int r = 0; r < 2; r++) {
            UF8 hv;
#pragma unroll
            for (int j = 0; j < 8; j++)
                hv.h[j] = (f16)xb[(size_t)(r * 128 + cg * 8 + j) * kS];
            // c = r*128 + cg*8 + j: kt = r*4 + (cg>>2); lane = (cg&3)*16 + (sl&15)
            int off = (r * 4 + (cg >> 2)) * 1024 + (sl >> 4) * 512
                      + ((cg & 3) * 16 + (sl & 15)) * 8;
            *(uint4*)(&AH[off]) = hv.u;
        }
    }
    __syncthreads();

    // wave's 6 o-tiles start at otile wid*6 (o = wid*96)
    const unsigned short* bhb = wh + ((size_t)(wid * 6) * 8) * 512 + (size_t)lane * 8;
    const unsigned short* blb = wl + ((size_t)(wid * 6) * 8) * 512 + (size_t)lane * 8;

    f32x4 acc[2][6] = {};
#pragma unroll
    for (int kt = 0; kt < 8; kt++) {
        f16x8 A[2];
#pragma unroll
        for (int mt = 0; mt < 2; mt++) {
            UF8 u;
            u.u = *(const uint4*)(&AH[kt * 1024 + mt * 512 + lane * 8]); A[mt] = u.v;
        }
#pragma unroll
        for (int nt = 0; nt < 6; nt++) {
            UF8 uh, ul;
            uh.u = *(const uint4*)(bhb + (size_t)(nt * 8 + kt) * 512);
            ul.u = *(const uint4*)(blb + (size_t)(nt * 8 + kt) * 512);
#pragma unroll
            for (int mt = 0; mt < 2; mt++) {
                acc[mt][nt] = __builtin_amdgcn_mfma_f32_16x16x32_f16(A[mt], uh.v, acc[mt][nt], 0, 0, 0);
                acc[mt][nt] = __builtin_amdgcn_mfma_f32_16x16x32_f16(A[mt], ul.v, acc[mt][nt], 0, 0, 0);
            }
        }
    }

    // Epilogue (r7-verified): D[row=s][col=o], row = quad*4+r, col = l15.
    constexpr float kQScale = 0.0625f * 1.4426950408889634f;
#pragma unroll
    for (int nt = 0; nt < 6; nt++) {
        int col = wid * 96 + nt * 16 + l15;   // global o, 0..767
        float bcol = bias[col];
        int oh  = col >> 8;                   // section (wave-uniform per nt)
        int cs  = col & 255;
        int h   = cs >> 5;
        int d   = cs & 31;
        int nh  = n * 8 + h;
#pragma unroll
        for (int mt = 0; mt < 2; mt++) {
            int row0 = s0 + mt * 16 + quad * 4;
            if (oh == 2) {
                // V -> 32x32 A-frag layout, t-scrambled within each 16-row tile:
                // slot lane_t = (quad&1)*32 + d, j = (quad>>1)*4 + r (inverse of rho').
                UF4 w;
#pragma unroll
                for (int r = 0; r < 4; r++) w.v[r] = (f16)(acc[mt][nt][r] + bcol);
                size_t off = (((size_t)nh * 144 + sb * 2 + mt) * 64 + (quad & 1) * 32 + d) * 8
                             + (quad >> 1) * 4;
                *(ushort4*)(Vp + off) = w.su;
            } else if (oh == 0) {
#pragma unroll
                for (int r = 0; r < 4; r++)
                    Kf[((size_t)nh * kS + row0 + r) * kDH + d] = (f16)(acc[mt][nt][r] + bcol);
            } else {
#pragma unroll
                for (int r = 0; r < 4; r++)
                    Qf[((size_t)nh * kS + row0 + r) * kDH + d] =
                        (f16)((acc[mt][nt][r] + bcol) * kQScale);
            }
        }
    }
}

// ---------------------------------------------------------------------------
// attn v10 = v9 with launch_bounds(192, 4): force regs <= 128 so HW fits
// 4 waves/SIMD (at (192,3) the ~170-reg cap gave exactly 3). Peak live-set
// hand count ~120 regs, so this should not spill — verify VGPR_Count <= 128.
// ---------------------------------------------------------------------------
#if __has_builtin(__builtin_amdgcn_fdot2)
#define LADD(acc, lou, hiu)                                                 \
    acc = __builtin_amdgcn_fdot2(__builtin_bit_cast(f16x2, lou), one2, acc, false); \
    acc = __builtin_amdgcn_fdot2(__builtin_bit_cast(f16x2, hiu), one2, acc, false);
#else
#define LADD(acc, lou, hiu)                                                 \
    {                                                                       \
        UF4 t; t.u.x = lou; t.u.y = hiu;                                    \
        acc += (float)t.v[0] + (float)t.v[1] + (float)t.v[2] + (float)t.v[3]; \
    }
#endif

#define SUBTILE(zq, VC, sidx, roff, lacc, oaccv)                            \
    {                                                                       \
        float e0 = EXP2(zq[roff + 0]), e1 = EXP2(zq[roff + 1]);             \
        float e2 = EXP2(zq[roff + 2]), e3 = EXP2(zq[roff + 3]);             \
        float e4 = EXP2(zq[roff + 4]), e5 = EXP2(zq[roff + 5]);             \
        float e6 = EXP2(zq[roff + 6]), e7 = EXP2(zq[roff + 7]);             \
        UF8 pw;                                                             \
        pw.u.x = pk2(e0, e1); pw.u.y = pk2(e2, e3);                         \
        pw.u.z = pk2(e4, e5); pw.u.w = pk2(e6, e7);                         \
        LADD(lacc, pw.u.x, pw.u.y)                                          \
        LADD(lacc, pw.u.z, pw.u.w)                                          \
        __builtin_amdgcn_s_setprio(1);                                      \
        oaccv = __builtin_amdgcn_mfma_f32_32x32x16_f16(VC[sidx], pw.v,      \
                                                       oaccv, 0, 0, 0);     \
        __builtin_amdgcn_s_setprio(0);                                      \
    }

#define ATTN_BODY(KC, VC, KN, VN)                                           \
    {                                                                       \
        UF8 u;                                                              \
        u.u = *(const uint4*)(kp + 1024);       KN[0] = u.v;                \
        u.u = *(const uint4*)(kp + 1040);       KN[1] = u.v;                \
        u.u = *(const uint4*)(vp + 1024);       VN[0] = u.v;                \
        u.u = *(const uint4*)(vp + 1536);       VN[1] = u.v;                \
        __builtin_amdgcn_s_setprio(1);                                      \
        f32x16 z0 = __builtin_amdgcn_mfma_f32_32x32x16_f16(KC[0], qf[0], zc, 0, 0, 0); \
        z0 = __builtin_amdgcn_mfma_f32_32x32x16_f16(KC[1], qf[1], z0, 0, 0, 0); \
        __builtin_amdgcn_s_setprio(0);                                      \
        SUBTILE(z0, VC, 0, 0, lsumA0, oacc0)                                \
        SUBTILE(z0, VC, 1, 8, lsumB0, oacc0)                                \
        __builtin_amdgcn_s_setprio(1);                                      \
        f32x16 z1 = __builtin_amdgcn_mfma_f32_32x32x16_f16(KC[0], qf[2], zc, 0, 0, 0); \
        z1 = __builtin_amdgcn_mfma_f32_32x32x16_f16(KC[1], qf[3], z1, 0, 0, 0); \
        __builtin_amdgcn_s_setprio(0);                                      \
        SUBTILE(z1, VC, 0, 0, lsumA1, oacc1)                                \
        SUBTILE(z1, VC, 1, 8, lsumB1, oacc1)                                \
        kp += 1024;                                                         \
        vp += 1024;                                                         \
    }

__global__ __launch_bounds__(192, 4) void attn_f16(const f16* __restrict__ Qf,
                                                   const f16* __restrict__ Kf,
                                                   const f16* __restrict__ Vp,
                                                   f16* __restrict__ attnF) {
    int h = blockIdx.x, qw = blockIdx.y, n = blockIdx.z;
    int nh = n * 8 + h;
    int tid  = threadIdx.x;
    int wid  = tid >> 6;           // t-chunk 0..2
    int lane = tid & 63;
    int c    = lane & 31;
    int hi   = lane >> 5;
    int sqb  = qw * 64;

    __shared__ __align__(16) float Ored[2][2][64][16];  // [src wave-1][qhalf][lane][reg swz]
    __shared__ float Lred[2][2][32];                    // [src wave-1][qhalf][col]

    // K: row-major [nh][s][32]; lane reads row (t0 + c), d-chunk hi*8 (+16 for kc=1)
    const f16* kp = Kf + (size_t)nh * kS * kDH + ((size_t)wid * 768 + c) * kDH + hi * 8;
    // V: scrambled A-frag [nh][tile 144][lane 64][8]
    const f16* vp = Vp + (size_t)nh * 144 * 512 + (size_t)wid * 48 * 512 + (size_t)lane * 8;

    f16x8 qf[4];
    {
        const f16* Qb = Qf + (size_t)nh * kS * kDH;
        UF8 u;
        u.u = *(const uint4*)(Qb + (size_t)(sqb + c) * kDH + hi * 8);           qf[0] = u.v;
        u.u = *(const uint4*)(Qb + (size_t)(sqb + c) * kDH + hi * 8 + 16);      qf[1] = u.v;
        u.u = *(const uint4*)(Qb + (size_t)(sqb + 32 + c) * kDH + hi * 8);      qf[2] = u.v;
        u.u = *(const uint4*)(Qb + (size_t)(sqb + 32 + c) * kDH + hi * 8 + 16); qf[3] = u.v;
    }

    f32x16 zc    = {};   // hoisted zero C-operand
    f32x16 oacc0 = {};   // qhalf0: O^T[d = (reg&3)+8*(reg>>2)+4*hi][sq = c]
    f32x16 oacc1 = {};   // qhalf1
    float lsumA0 = 0.f, lsumB0 = 0.f, lsumA1 = 0.f, lsumB1 = 0.f;
    const f16x2 one2 = {(_Float16)1.0f, (_Float16)1.0f};

    f16x8 kA[2], kB[2], vA[2], vB[2];
    {
        UF8 u;
        u.u = *(const uint4*)(kp);        kA[0] = u.v;
        u.u = *(const uint4*)(kp + 16);   kA[1] = u.v;
        u.u = *(const uint4*)(vp);        vA[0] = u.v;
        u.u = *(const uint4*)(vp + 512);  vA[1] = u.v;
    }

    // 24 bodies of 32 t per wave, ping-pong x2; tail over-reads land in the
    // adjacent ws buffers (allocated, values unused).
    for (int it = 0; it < 12; it++) {
        ATTN_BODY(kA, vA, kB, vB)
        ATTN_BODY(kB, vB, kA, vA)
    }

    float lsum0 = lsumA0 + lsumB0;
    float lsum1 = lsumA1 + lsumB1;
    // lanes c and c+32 hold complementary t-halves -> single cross-half reduce
    lsum0 += __shfl_xor(lsum0, 32);
    lsum1 += __shfl_xor(lsum1, 32);

    // cross-wave combine: waves 1,2 dump partials; wave 0 reduces + writes.
    // Column slot swizzled by g ^ ((lane>>1)&3) (kills the r1 bank conflicts).
    int gsw = (lane >> 1) & 3;
    if (wid > 0) {
#pragma unroll
        for (int g = 0; g < 4; g++) {
            f32x4 t0 = {oacc0[g * 4 + 0], oacc0[g * 4 + 1], oacc0[g * 4 + 2], oacc0[g * 4 + 3]};
            f32x4 t1 = {oacc1[g * 4 + 0], oacc1[g * 4 + 1], oacc1[g * 4 + 2], oacc1[g * 4 + 3]};
            *(f32x4*)(&Ored[wid - 1][0][lane][(g ^ gsw) * 4]) = t0;
            *(f32x4*)(&Ored[wid - 1][1][lane][(g ^ gsw) * 4]) = t1;
        }
        if (lane < 32) {
            Lred[wid - 1][0][lane] = lsum0;
            Lred[wid - 1][1][lane] = lsum1;
        }
    }
    __syncthreads();
    if (wid != 0) return;

#pragma unroll
    for (int g = 0; g < 4; g++) {
        f32x4 a0 = *(const f32x4*)(&Ored[0][0][lane][(g ^ gsw) * 4]);
        f32x4 b0 = *(const f32x4*)(&Ored[1][0][lane][(g ^ gsw) * 4]);
        f32x4 a1 = *(const f32x4*)(&Ored[0][1][lane][(g ^ gsw) * 4]);
        f32x4 b1 = *(const f32x4*)(&Ored[1][1][lane][(g ^ gsw) * 4]);
#pragma unroll
        for (int r = 0; r < 4; r++) {
            oacc0[g * 4 + r] += a0[r] + b0[r];
            oacc1[g * 4 + r] += a1[r] + b1[r];
        }
    }
    lsum0 += Lred[0][0][c] + Lred[1][0][c];
    lsum1 += Lred[0][1][c] + Lred[1][1][c];

    // epilogue: normalize; write attnF in gemm_out B-frag order.
    // reg group g holds d = 8g + 4hi + r -> lane_t = g*16 + (c&15), j = 4hi + r.
#define EPI(oaccv, lsumv, p)                                                \
    {                                                                       \
        float inv = 1.0f / lsumv;                                           \
        int stile = qw * 4 + (p) * 2 + (c >> 4);                            \
        size_t base = ((size_t)(n * 144 + stile) * 8 + h) * 512             \
                      + (size_t)(c & 15) * 8 + hi * 4;                      \
        _Pragma("unroll")                                                   \
        for (int g = 0; g < 4; g++) {                                       \
            UF4 w;                                                          \
            _Pragma("unroll")                                               \
            for (int r = 0; r < 4; r++) w.v[r] = (f16)(oaccv[g * 4 + r] * inv); \
            *(uint2*)(attnF + base + g * 128) = w.u;                        \
        }                                                                   \
    }
    EPI(oacc0, lsum0, 0)
    EPI(oacc1, lsum1, 1)
#undef EPI
}

// ---------------------------------------------------------------------------
// gemm_out v2 (r4): K-split x2. 128-thr blocks (2 waves); wave wid handles
// kt wid*4..wid*4+3, combine via one xor-swizzled LDS dump.
// Grid (8, 36, 4) x 128 thr.
// ---------------------------------------------------------------------------
__global__ __launch_bounds__(128) void gemm_out(const f16* __restrict__ wp,
                                                const f16* __restrict__ attnF,
                                                const float* __restrict__ bias,
                                                float* __restrict__ out) {
    int ob = blockIdx.x, sb = blockIdx.y, n = blockIdx.z;
    int tid  = threadIdx.x;
    int wid  = tid >> 6;          // K-half 0..1
    int lane = tid & 63;
    int l15  = lane & 15;
    int quad = lane >> 4;

    __shared__ __align__(16) float Ocomb[64][32];   // 8 KB, xor-swizzled columns

    const f16* ap = wp + ((size_t)(ob * 2) * 8 + wid * 4) * 512 + (size_t)lane * 8;
    const f16* bp = attnF + ((size_t)(n * 144 + sb * 4) * 8 + wid * 4) * 512 + (size_t)lane * 8;

    f16x8 af[2], bf[4], naf[2], nbf[4];
    {
        UF8 u;
#pragma unroll
        for (int i = 0; i < 2; i++) { u.u = *(const uint4*)(ap + (i * 8) * 512); af[i] = u.v; }
#pragma unroll
        for (int i = 0; i < 4; i++) { u.u = *(const uint4*)(bp + (i * 8) * 512); bf[i] = u.v; }
    }

    f32x4 acc[2][4] = {};
#pragma unroll
    for (int t = 0; t < 4; t++) {
        if (t < 3) {
            UF8 u;
#pragma unroll
            for (int i = 0; i < 2; i++) { u.u = *(const uint4*)(ap + (i * 8 + t + 1) * 512); naf[i] = u.v; }
#pragma unroll
            for (int i = 0; i < 4; i++) { u.u = *(const uint4*)(bp + (i * 8 + t + 1) * 512); nbf[i] = u.v; }
        }
#pragma unroll
        for (int mt = 0; mt < 2; mt++)
#pragma unroll
            for (int nt = 0; nt < 4; nt++)
                acc[mt][nt] = __builtin_amdgcn_mfma_f32_16x16x32_f16(af[mt], bf[nt],
                                                                     acc[mt][nt], 0, 0, 0);
#pragma unroll
        for (int i = 0; i < 2; i++) af[i] = naf[i];
#pragma unroll
        for (int i = 0; i < 4; i++) bf[i] = nbf[i];
    }

    // cross-wave K combine: wave 1 dumps, wave 0 adds.
    int csw = lane & 7;
    if (wid == 1) {
#pragma unroll
        for (int mt = 0; mt < 2; mt++)
#pragma unroll
            for (int nt = 0; nt < 4; nt++) {
                int g = mt * 4 + nt;
                *(f32x4*)(&Ocomb[lane][(g ^ csw) * 4]) = acc[mt][nt];
            }
    }
    __syncthreads();
    if (wid != 0) return;

#pragma unroll
    for (int mt = 0; mt < 2; mt++) {
        int row0 = ob * 32 + mt * 16 + quad * 4;   // o
#pragma unroll
        for (int nt = 0; nt < 4; nt++) {
            int g = mt * 4 + nt;
            f32x4 other = *(const f32x4*)(&Ocomb[lane][(g ^ csw) * 4]);
            int col = sb * 64 + nt * 16 + l15;     // s
#pragma unroll
            for (int r = 0; r < 4; r++)
                out[((size_t)n * kDV + row0 + r) * kS + col] =
                    acc[mt][nt][r] + other[r] + bias[row0 + r];
        }
    }
}

// ---------------------------------------------------------------------------
extern "C" void kernel_launch(void* const* d_in, const int* in_sizes, int n_in,
                              void* d_out, int out_size, void* d_ws, size_t ws_size,
                              hipStream_t stream) {
    const float* x      = (const float*)d_in[0];
    const float* w_qkv  = (const float*)d_in[1];
    const float* b_qkv  = (const float*)d_in[2];
    const float* w_proj = (const float*)d_in[3];
    const float* b_proj = (const float*)d_in[4];
    float* out = (float*)d_out;

    constexpr size_t kXE = (size_t)kN * kS * kC;     // 2,359,296
    unsigned short* wh = (unsigned short*)d_ws;      // w_qkv B-frag f16-hi
    unsigned short* wl = wh + 196608;                // w_qkv B-frag f16-lo
    f16* wpF   = (f16*)(wl + 196608);                // w_proj A-frag f16
    f16* Qf    = wpF + 65536;                        // [32 nh][2304][32]
    f16* Kf    = Qf + kXE;
    f16* Vp    = Kf + kXE;                           // [32 nh][144][64][8] scrambled A-frag
    f16* attnF = Vp + kXE;                           // B-frag [n][144][8][512]

    prep_w<<<dim3(128), 256, 0, stream>>>(w_qkv, w_proj, wh, wl, wpF);

    gemm_qkv<<<dim3(72, 1, 4), 512, 0, stream>>>(x, wh, wl, b_qkv, Qf, Kf, Vp);

    attn_f16<<<dim3(8, 36, 4), 192, 0, stream>>>(Qf, Kf, Vp, attnF);

    gemm_out<<<dim3(8, 36, 4), 128, 0, stream>>>(wpF, attnF, b_proj, out);
}

// Round 6
// 119.897 us; speedup vs baseline: 1.0739x; 1.0739x over previous
//
#include <hip/hip_runtime.h>
#include <cstdint>

// Problem constants
constexpr int kN   = 4;
constexpr int kC   = 256;
constexpr int kS   = 2304;   // 48*48
constexpr int kDK  = 256;
constexpr int kDV  = 256;
constexpr int kDH  = 32;     // head dim
constexpr int kO   = 768;    // 2*DK + DV

typedef __bf16    bf16x8 __attribute__((ext_vector_type(8)));
typedef float     f32x4  __attribute__((ext_vector_type(4)));
typedef float     f32x16 __attribute__((ext_vector_type(16)));
typedef _Float16  f16;
typedef _Float16  f16x2  __attribute__((ext_vector_type(2)));
typedef _Float16  f16x4  __attribute__((ext_vector_type(4)));
typedef _Float16  f16x8  __attribute__((ext_vector_type(8)));

union U4  { uint4 u; bf16x8 v; unsigned short s[8]; };
union F4  { float4 f; float a[4]; };
union UF8 { uint4 u; f16x8 v; f16 h[8]; };
union UF4 { uint2 u; f16x4 v; ushort4 su; };

#if __has_builtin(__builtin_amdgcn_exp2f)
#define EXP2(x) __builtin_amdgcn_exp2f(x)
#else
#define EXP2(x) exp2f(x)
#endif

__device__ inline unsigned int pk2(float a, float b) {
    auto p = __builtin_amdgcn_cvt_pkrtz(a, b);
    return __builtin_bit_cast(unsigned int, p);
}
// f16 hi/lo split: h captures 11 mantissa bits, l the next 11 (~22-bit exact).
__device__ inline void split2f(float v, f16& h, f16& l) {
    h = (f16)v;
    l = (f16)(v - (float)h);
}

// Fragment layouts:
// 16x16x32 (correctness-verified rounds 6-10; dtype-independent):
//   A/B-frag elem (row, k): lane = ((k>>3)&3)*16 + (row&15), j = k&7
//   C-layout: D[row = (lane>>4)*4 + reg][col = lane&15].
// 32x32x16 (attn core, r1-verified):
//   A-frag (row, k): lane = (k>>3)*32 + (row&31), j = k&7  (B symmetric, col=lane&31)
//   C-layout: D[row = (reg&3) + 8*(reg>>2) + 4*(lane>>5)][col = lane&31].

// ---------------------------------------------------------------------------
// prep_w (r3-verified): w_qkv -> SPLIT-F16 B-frags wh/wl [otile 48][kt 8]
// [lane][8]; w_proj -> f16 A-frag wp. Grid 128.
// ---------------------------------------------------------------------------
__global__ __launch_bounds__(256) void prep_w(const float* __restrict__ w_qkv,
                                              const float* __restrict__ w_proj,
                                              unsigned short* __restrict__ wh,
                                              unsigned short* __restrict__ wl,
                                              f16* __restrict__ wp) {
    int idx = blockIdx.x * 256 + threadIdx.x;
    if (idx < 24576) {           // w_qkv: 768 o x 32 c-groups
        int o = idx >> 5, cg = idx & 31;
        F4 a0, a1;
        a0.f = *(const float4*)(w_qkv + (size_t)o * kC + cg * 8);
        a1.f = *(const float4*)(w_qkv + (size_t)o * kC + cg * 8 + 4);
        UF8 hv, lv;
#pragma unroll
        for (int j = 0; j < 4; j++) split2f(a0.a[j], hv.h[j], lv.h[j]);
#pragma unroll
        for (int j = 0; j < 4; j++) split2f(a1.a[j], hv.h[j + 4], lv.h[j + 4]);
        size_t frag = ((size_t)(o >> 4) * 8 + (cg >> 2)) * 512 + ((cg & 3) * 16 + (o & 15)) * 8;
        *(uint4*)(wh + frag) = hv.u;
        *(uint4*)(wl + frag) = lv.u;
    } else {                     // w_proj: 256 o x 32 dv-groups
        int i2 = idx - 24576;
        int o = i2 >> 5, cg = i2 & 31;
        F4 a0, a1;
        a0.f = *(const float4*)(w_proj + (size_t)o * kDV + cg * 8);
        a1.f = *(const float4*)(w_proj + (size_t)o * kDV + cg * 8 + 4);
        UF8 w;
#pragma unroll
        for (int j = 0; j < 4; j++) w.h[j] = (f16)a0.a[j];
#pragma unroll
        for (int j = 0; j < 4; j++) w.h[j + 4] = (f16)a1.a[j];
        size_t frag = ((size_t)(o >> 4) * 8 + (cg >> 2)) * 512 + ((cg & 3) * 16 + (o & 15)) * 8;
        *(uint4*)(wp + frag) = w.u;
    }
}

// ---------------------------------------------------------------------------
// gemm_qkv v4 (r4-verified, 118.4 us total config — restored after the v5
// makespan regression: 288 big blocks -> 3T makespan vs v4's 2T).
// 512-thr blocks (8 waves) cover 64 s x 256 o; each wave = 64s x 32o
// (acc 4x2). x staged once per block as single-f16 A-frags (32 KB LDS).
// 2-MFMA split-f16-w scheme (r3-verified numerics). Grid (36, 3, 4).
// ---------------------------------------------------------------------------
__global__ __launch_bounds__(512) void gemm_qkv(const float* __restrict__ x,
                                                const unsigned short* __restrict__ wh,
                                                const unsigned short* __restrict__ wl,
                                                const float* __restrict__ bias,
                                                f16* __restrict__ Qf,
                                                f16* __restrict__ Kf,
                                                f16* __restrict__ Vp) {
    int sb = blockIdx.x, oh = blockIdx.y, n = blockIdx.z;
    int tid  = threadIdx.x;
    int wid  = tid >> 6;          // o-strip 0..7 (32 o each)
    int lane = tid & 63;
    int l15  = lane & 15;
    int quad = lane >> 4;
    int s0   = sb * 64;

    __shared__ unsigned short AH[16384];   // f16 bits, [kt 8][mt 4][lane 64][8]

    // ---- stage x strip [64 s][256 c] -> f16 A-frag LDS ----
    {
        int cg = tid >> 6;          // 0..7
        int sl = tid & 63;          // s within strip
        const float* xb = x + (size_t)n * kC * kS + s0 + sl;
#pragma unroll
        for (int r = 0; r < 4; r++) {
            UF8 hv;
#pragma unroll
            for (int j = 0; j < 8; j++)
                hv.h[j] = (f16)xb[(size_t)(r * 64 + cg * 8 + j) * kS];
            // c = r*64 + cg*8 + j: kt = r*2 + (cg>>2); lane = (cg&3)*16 + (sl&15)
            int off = (r * 2 + (cg >> 2)) * 2048 + (sl >> 4) * 512
                      + ((cg & 3) * 16 + (sl & 15)) * 8;
            *(uint4*)(&AH[off]) = hv.u;
        }
    }
    __syncthreads();

    const unsigned short* bhb = wh + ((size_t)(oh * 16 + wid * 2) * 8) * 512 + (size_t)lane * 8;
    const unsigned short* blb = wl + ((size_t)(oh * 16 + wid * 2) * 8) * 512 + (size_t)lane * 8;

    f32x4 acc[4][2] = {};
#pragma unroll
    for (int kt = 0; kt < 8; kt++) {
        f16x8 Bh[2], Bl[2];
#pragma unroll
        for (int nt = 0; nt < 2; nt++) {
            UF8 u;
            u.u = *(const uint4*)(bhb + (size_t)(nt * 8 + kt) * 512); Bh[nt] = u.v;
            u.u = *(const uint4*)(blb + (size_t)(nt * 8 + kt) * 512); Bl[nt] = u.v;
        }
        f16x8 A[4];
#pragma unroll
        for (int mt = 0; mt < 4; mt++) {
            UF8 u;
            u.u = *(const uint4*)(&AH[kt * 2048 + mt * 512 + lane * 8]); A[mt] = u.v;
        }
#pragma unroll
        for (int mt = 0; mt < 4; mt++)
#pragma unroll
            for (int nt = 0; nt < 2; nt++) {
                acc[mt][nt] = __builtin_amdgcn_mfma_f32_16x16x32_f16(A[mt], Bh[nt], acc[mt][nt], 0, 0, 0);
                acc[mt][nt] = __builtin_amdgcn_mfma_f32_16x16x32_f16(A[mt], Bl[nt], acc[mt][nt], 0, 0, 0);
            }
    }

    // Epilogue (r7-verified): D[row=s][col=o], row = quad*4+r, col = l15.
    constexpr float kQScale = 0.0625f * 1.4426950408889634f;
#pragma unroll
    for (int nt = 0; nt < 2; nt++) {
        int col = oh * 256 + wid * 32 + nt * 16 + l15;
        float bcol = bias[col];
        int h   = (col >> 5) & 7;
        int d   = col & 31;
        int nh  = n * 8 + h;
#pragma unroll
        for (int mt = 0; mt < 4; mt++) {
            int row0 = s0 + mt * 16 + quad * 4;
            if (oh == 2) {
                // V -> 32x32 A-frag layout, t-scrambled within each 16-row tile:
                // slot lane_t = (quad&1)*32 + d, j = (quad>>1)*4 + r (inverse of rho').
                UF4 w;
#pragma unroll
                for (int r = 0; r < 4; r++) w.v[r] = (f16)(acc[mt][nt][r] + bcol);
                size_t off = (((size_t)nh * 144 + sb * 4 + mt) * 64 + (quad & 1) * 32 + d) * 8
                             + (quad >> 1) * 4;
                *(ushort4*)(Vp + off) = w.su;
            } else if (oh == 0) {
#pragma unroll
                for (int r = 0; r < 4; r++)
                    Kf[((size_t)nh * kS + row0 + r) * kDH + d] = (f16)(acc[mt][nt][r] + bcol);
            } else {
#pragma unroll
                for (int r = 0; r < 4; r++)
                    Qf[((size_t)nh * kS + row0 + r) * kDH + d] =
                        (f16)((acc[mt][nt][r] + bcol) * kQScale);
            }
        }
    }
}

// ---------------------------------------------------------------------------
// attn v11: r4 structure (Q64 per wave, (192,3) — the (192,4) force in r5
// SPILLED and regressed; live set is in (128,170]) + PREFETCH DEPTH 2 via
// 3-buffer rotation. Depth-1 ping-pong gave only ~1 body (~300 cyc) of
// cover for the ~200-300 cyc L2-hit latency — zero slack; stall signature:
// MfmaUtil+VALUBusy ~53%, waves stalled half the time. Depth-2 gives ~600
// cyc cover at +16 regs (kC/vC), still under the 170-reg cap of 3/SIMD.
// Tail prefetch over-reads 2 bodies (4 KB) into adjacent allocated ws
// buffers (values unused). Grid (8 h, 36 qw, 4 n) x 192 thr.
// ---------------------------------------------------------------------------
#if __has_builtin(__builtin_amdgcn_fdot2)
#define LADD(acc, lou, hiu)                                                 \
    acc = __builtin_amdgcn_fdot2(__builtin_bit_cast(f16x2, lou), one2, acc, false); \
    acc = __builtin_amdgcn_fdot2(__builtin_bit_cast(f16x2, hiu), one2, acc, false);
#else
#define LADD(acc, lou, hiu)                                                 \
    {                                                                       \
        UF4 t; t.u.x = lou; t.u.y = hiu;                                    \
        acc += (float)t.v[0] + (float)t.v[1] + (float)t.v[2] + (float)t.v[3]; \
    }
#endif

#define SUBTILE(zq, VC, sidx, roff, lacc, oaccv)                            \
    {                                                                       \
        float e0 = EXP2(zq[roff + 0]), e1 = EXP2(zq[roff + 1]);             \
        float e2 = EXP2(zq[roff + 2]), e3 = EXP2(zq[roff + 3]);             \
        float e4 = EXP2(zq[roff + 4]), e5 = EXP2(zq[roff + 5]);             \
        float e6 = EXP2(zq[roff + 6]), e7 = EXP2(zq[roff + 7]);             \
        UF8 pw;                                                             \
        pw.u.x = pk2(e0, e1); pw.u.y = pk2(e2, e3);                         \
        pw.u.z = pk2(e4, e5); pw.u.w = pk2(e6, e7);                         \
        LADD(lacc, pw.u.x, pw.u.y)                                          \
        LADD(lacc, pw.u.z, pw.u.w)                                          \
        __builtin_amdgcn_s_setprio(1);                                      \
        oaccv = __builtin_amdgcn_mfma_f32_32x32x16_f16(VC[sidx], pw.v,      \
                                                       oaccv, 0, 0, 0);     \
        __builtin_amdgcn_s_setprio(0);                                      \
    }

// Body: compute with (KC,VC); prefetch body i+2 into (KN,VN).
#define ATTN_BODY(KC, VC, KN, VN)                                           \
    {                                                                       \
        UF8 u;                                                              \
        u.u = *(const uint4*)(kp + 2048);       KN[0] = u.v;                \
        u.u = *(const uint4*)(kp + 2064);       KN[1] = u.v;                \
        u.u = *(const uint4*)(vp + 2048);       VN[0] = u.v;                \
        u.u = *(const uint4*)(vp + 2560);       VN[1] = u.v;                \
        __builtin_amdgcn_s_setprio(1);                                      \
        f32x16 z0 = __builtin_amdgcn_mfma_f32_32x32x16_f16(KC[0], qf[0], zc, 0, 0, 0); \
        z0 = __builtin_amdgcn_mfma_f32_32x32x16_f16(KC[1], qf[1], z0, 0, 0, 0); \
        __builtin_amdgcn_s_setprio(0);                                      \
        SUBTILE(z0, VC, 0, 0, lsumA0, oacc0)                                \
        SUBTILE(z0, VC, 1, 8, lsumB0, oacc0)                                \
        __builtin_amdgcn_s_setprio(1);                                      \
        f32x16 z1 = __builtin_amdgcn_mfma_f32_32x32x16_f16(KC[0], qf[2], zc, 0, 0, 0); \
        z1 = __builtin_amdgcn_mfma_f32_32x32x16_f16(KC[1], qf[3], z1, 0, 0, 0); \
        __builtin_amdgcn_s_setprio(0);                                      \
        SUBTILE(z1, VC, 0, 0, lsumA1, oacc1)                                \
        SUBTILE(z1, VC, 1, 8, lsumB1, oacc1)                                \
        kp += 1024;                                                         \
        vp += 1024;                                                         \
    }

__global__ __launch_bounds__(192, 3) void attn_f16(const f16* __restrict__ Qf,
                                                   const f16* __restrict__ Kf,
                                                   const f16* __restrict__ Vp,
                                                   f16* __restrict__ attnF) {
    int h = blockIdx.x, qw = blockIdx.y, n = blockIdx.z;
    int nh = n * 8 + h;
    int tid  = threadIdx.x;
    int wid  = tid >> 6;           // t-chunk 0..2
    int lane = tid & 63;
    int c    = lane & 31;
    int hi   = lane >> 5;
    int sqb  = qw * 64;

    __shared__ __align__(16) float Ored[2][2][64][16];  // [src wave-1][qhalf][lane][reg swz]
    __shared__ float Lred[2][2][32];                    // [src wave-1][qhalf][col]

    // K: row-major [nh][s][32]; lane reads row (t0 + c), d-chunk hi*8 (+16 for kc=1)
    const f16* kp = Kf + (size_t)nh * kS * kDH + ((size_t)wid * 768 + c) * kDH + hi * 8;
    // V: scrambled A-frag [nh][tile 144][lane 64][8]
    const f16* vp = Vp + (size_t)nh * 144 * 512 + (size_t)wid * 48 * 512 + (size_t)lane * 8;

    f16x8 qf[4];
    {
        const f16* Qb = Qf + (size_t)nh * kS * kDH;
        UF8 u;
        u.u = *(const uint4*)(Qb + (size_t)(sqb + c) * kDH + hi * 8);           qf[0] = u.v;
        u.u = *(const uint4*)(Qb + (size_t)(sqb + c) * kDH + hi * 8 + 16);      qf[1] = u.v;
        u.u = *(const uint4*)(Qb + (size_t)(sqb + 32 + c) * kDH + hi * 8);      qf[2] = u.v;
        u.u = *(const uint4*)(Qb + (size_t)(sqb + 32 + c) * kDH + hi * 8 + 16); qf[3] = u.v;
    }

    f32x16 zc    = {};   // hoisted zero C-operand
    f32x16 oacc0 = {};   // qhalf0: O^T[d = (reg&3)+8*(reg>>2)+4*hi][sq = c]
    f32x16 oacc1 = {};   // qhalf1
    float lsumA0 = 0.f, lsumB0 = 0.f, lsumA1 = 0.f, lsumB1 = 0.f;
    const f16x2 one2 = {(_Float16)1.0f, (_Float16)1.0f};

    // 3-buffer rotation: body i uses set (i%3); loads land 2 bodies ahead.
    f16x8 kA[2], kB[2], kC_[2], vA[2], vB[2], vC_[2];
    {
        UF8 u;
        u.u = *(const uint4*)(kp);           kA[0] = u.v;
        u.u = *(const uint4*)(kp + 16);      kA[1] = u.v;
        u.u = *(const uint4*)(vp);           vA[0] = u.v;
        u.u = *(const uint4*)(vp + 512);     vA[1] = u.v;
        u.u = *(const uint4*)(kp + 1024);    kB[0] = u.v;
        u.u = *(const uint4*)(kp + 1040);    kB[1] = u.v;
        u.u = *(const uint4*)(vp + 1024);    vB[0] = u.v;
        u.u = *(const uint4*)(vp + 1536);    vB[1] = u.v;
    }

    // 24 bodies of 32 t per wave (8 iters x 3); prefetch depth 2.
    for (int it = 0; it < 8; it++) {
        ATTN_BODY(kA, vA, kC_, vC_)
        ATTN_BODY(kB, vB, kA, vA)
        ATTN_BODY(kC_, vC_, kB, vB)
    }

    float lsum0 = lsumA0 + lsumB0;
    float lsum1 = lsumA1 + lsumB1;
    // lanes c and c+32 hold complementary t-halves -> single cross-half reduce
    lsum0 += __shfl_xor(lsum0, 32);
    lsum1 += __shfl_xor(lsum1, 32);

    // cross-wave combine: waves 1,2 dump partials; wave 0 reduces + writes.
    // Column slot swizzled by g ^ ((lane>>1)&3) (kills the r1 bank conflicts).
    int gsw = (lane >> 1) & 3;
    if (wid > 0) {
#pragma unroll
        for (int g = 0; g < 4; g++) {
            f32x4 t0 = {oacc0[g * 4 + 0], oacc0[g * 4 + 1], oacc0[g * 4 + 2], oacc0[g * 4 + 3]};
            f32x4 t1 = {oacc1[g * 4 + 0], oacc1[g * 4 + 1], oacc1[g * 4 + 2], oacc1[g * 4 + 3]};
            *(f32x4*)(&Ored[wid - 1][0][lane][(g ^ gsw) * 4]) = t0;
            *(f32x4*)(&Ored[wid - 1][1][lane][(g ^ gsw) * 4]) = t1;
        }
        if (lane < 32) {
            Lred[wid - 1][0][lane] = lsum0;
            Lred[wid - 1][1][lane] = lsum1;
        }
    }
    __syncthreads();
    if (wid != 0) return;

#pragma unroll
    for (int g = 0; g < 4; g++) {
        f32x4 a0 = *(const f32x4*)(&Ored[0][0][lane][(g ^ gsw) * 4]);
        f32x4 b0 = *(const f32x4*)(&Ored[1][0][lane][(g ^ gsw) * 4]);
        f32x4 a1 = *(const f32x4*)(&Ored[0][1][lane][(g ^ gsw) * 4]);
        f32x4 b1 = *(const f32x4*)(&Ored[1][1][lane][(g ^ gsw) * 4]);
#pragma unroll
        for (int r = 0; r < 4; r++) {
            oacc0[g * 4 + r] += a0[r] + b0[r];
            oacc1[g * 4 + r] += a1[r] + b1[r];
        }
    }
    lsum0 += Lred[0][0][c] + Lred[1][0][c];
    lsum1 += Lred[0][1][c] + Lred[1][1][c];

    // epilogue: normalize; write attnF in gemm_out B-frag order.
    // reg group g holds d = 8g + 4hi + r -> lane_t = g*16 + (c&15), j = 4hi + r.
#define EPI(oaccv, lsumv, p)                                                \
    {                                                                       \
        float inv = 1.0f / lsumv;                                           \
        int stile = qw * 4 + (p) * 2 + (c >> 4);                            \
        size_t base = ((size_t)(n * 144 + stile) * 8 + h) * 512             \
                      + (size_t)(c & 15) * 8 + hi * 4;                      \
        _Pragma("unroll")                                                   \
        for (int g = 0; g < 4; g++) {                                       \
            UF4 w;                                                          \
            _Pragma("unroll")                                               \
            for (int r = 0; r < 4; r++) w.v[r] = (f16)(oaccv[g * 4 + r] * inv); \
            *(uint2*)(attnF + base + g * 128) = w.u;                        \
        }                                                                   \
    }
    EPI(oacc0, lsum0, 0)
    EPI(oacc1, lsum1, 1)
#undef EPI
}

// ---------------------------------------------------------------------------
// gemm_out v2 (r4-verified): K-split x2. 128-thr blocks (2 waves); wave wid
// handles kt wid*4..wid*4+3, combine via one xor-swizzled LDS dump.
// Grid (8, 36, 4) x 128 thr.
// ---------------------------------------------------------------------------
__global__ __launch_bounds__(128) void gemm_out(const f16* __restrict__ wp,
                                                const f16* __restrict__ attnF,
                                                const float* __restrict__ bias,
                                                float* __restrict__ out) {
    int ob = blockIdx.x, sb = blockIdx.y, n = blockIdx.z;
    int tid  = threadIdx.x;
    int wid  = tid >> 6;          // K-half 0..1
    int lane = tid & 63;
    int l15  = lane & 15;
    int quad = lane >> 4;

    __shared__ __align__(16) float Ocomb[64][32];   // 8 KB, xor-swizzled columns

    const f16* ap = wp + ((size_t)(ob * 2) * 8 + wid * 4) * 512 + (size_t)lane * 8;
    const f16* bp = attnF + ((size_t)(n * 144 + sb * 4) * 8 + wid * 4) * 512 + (size_t)lane * 8;

    f16x8 af[2], bf[4], naf[2], nbf[4];
    {
        UF8 u;
#pragma unroll
        for (int i = 0; i < 2; i++) { u.u = *(const uint4*)(ap + (i * 8) * 512); af[i] = u.v; }
#pragma unroll
        for (int i = 0; i < 4; i++) { u.u = *(const uint4*)(bp + (i * 8) * 512); bf[i] = u.v; }
    }

    f32x4 acc[2][4] = {};
#pragma unroll
    for (int t = 0; t < 4; t++) {
        if (t < 3) {
            UF8 u;
#pragma unroll
            for (int i = 0; i < 2; i++) { u.u = *(const uint4*)(ap + (i * 8 + t + 1) * 512); naf[i] = u.v; }
#pragma unroll
            for (int i = 0; i < 4; i++) { u.u = *(const uint4*)(bp + (i * 8 + t + 1) * 512); nbf[i] = u.v; }
        }
#pragma unroll
        for (int mt = 0; mt < 2; mt++)
#pragma unroll
            for (int nt = 0; nt < 4; nt++)
                acc[mt][nt] = __builtin_amdgcn_mfma_f32_16x16x32_f16(af[mt], bf[nt],
                                                                     acc[mt][nt], 0, 0, 0);
#pragma unroll
        for (int i = 0; i < 2; i++) af[i] = naf[i];
#pragma unroll
        for (int i = 0; i < 4; i++) bf[i] = nbf[i];
    }

    // cross-wave K combine: wave 1 dumps, wave 0 adds.
    int csw = lane & 7;
    if (wid == 1) {
#pragma unroll
        for (int mt = 0; mt < 2; mt++)
#pragma unroll
            for (int nt = 0; nt < 4; nt++) {
                int g = mt * 4 + nt;
                *(f32x4*)(&Ocomb[lane][(g ^ csw) * 4]) = acc[mt][nt];
            }
    }
    __syncthreads();
    if (wid != 0) return;

#pragma unroll
    for (int mt = 0; mt < 2; mt++) {
        int row0 = ob * 32 + mt * 16 + quad * 4;   // o
#pragma unroll
        for (int nt = 0; nt < 4; nt++) {
            int g = mt * 4 + nt;
            f32x4 other = *(const f32x4*)(&Ocomb[lane][(g ^ csw) * 4]);
            int col = sb * 64 + nt * 16 + l15;     // s
#pragma unroll
            for (int r = 0; r < 4; r++)
                out[((size_t)n * kDV + row0 + r) * kS + col] =
                    acc[mt][nt][r] + other[r] + bias[row0 + r];
        }
    }
}

// ---------------------------------------------------------------------------
extern "C" void kernel_launch(void* const* d_in, const int* in_sizes, int n_in,
                              void* d_out, int out_size, void* d_ws, size_t ws_size,
                              hipStream_t stream) {
    const float* x      = (const float*)d_in[0];
    const float* w_qkv  = (const float*)d_in[1];
    const float* b_qkv  = (const float*)d_in[2];
    const float* w_proj = (const float*)d_in[3];
    const float* b_proj = (const float*)d_in[4];
    float* out = (float*)d_out;

    constexpr size_t kXE = (size_t)kN * kS * kC;     // 2,359,296
    unsigned short* wh = (unsigned short*)d_ws;      // w_qkv B-frag f16-hi
    unsigned short* wl = wh + 196608;                // w_qkv B-frag f16-lo
    f16* wpF   = (f16*)(wl + 196608);                // w_proj A-frag f16
    f16* Qf    = wpF + 65536;                        // [32 nh][2304][32]
    f16* Kf    = Qf + kXE;
    f16* Vp    = Kf + kXE;                           // [32 nh][144][64][8] scrambled A-frag
    f16* attnF = Vp + kXE;                           // B-frag [n][144][8][512]

    prep_w<<<dim3(128), 256, 0, stream>>>(w_qkv, w_proj, wh, wl, wpF);

    gemm_qkv<<<dim3(36, 3, 4), 512, 0, stream>>>(x, wh, wl, b_qkv, Qf, Kf, Vp);

    attn_f16<<<dim3(8, 36, 4), 192, 0, stream>>>(Qf, Kf, Vp, attnF);

    gemm_out<<<dim3(8, 36, 4), 128, 0, stream>>>(wpF, attnF, b_proj, out);
}